// Round 1
// baseline (3576.511 us; speedup 1.0000x reference)
//
#include <hip/hip_runtime.h>
#include <math.h>

// CapsuleLayer dynamic routing, MI355X fp32. Round 3: latency-bound fixes.
// B=64, In=2048, Din=16, Nc=32, Dc=32, ROUTINGS=3.
// Identity: b starts at 0 => logits_t = hat . (v1+..+v_{t-1}); never store b or hat.
//
// vs round 2 (718 us): kernel was latency-bound (occ 22%, VALU 21%, true beyond-L2
// BW ~0.6 TB/s). Changes:
//  - B_CHUNK 16->8: grid 512->1024 blocks (4 blocks/CU), acc 64->32 VGPR.
//  - XCD-clustered swizzle: 8 bg-siblings of an i-group land back-to-back on one
//    XCD so the 1 MB W slice is shared in that XCD's L2.
//  - x staged fully up front (8 KB LDS, ONE barrier). Phase 0: no barriers in the
//    il loop at all; W double-buffered in half-il register chunks -> loads stay
//    in flight across iterations (no vmcnt(0) drains).
//  - Phase 1: hat kept in REGISTERS (hat_s 64 KB LDS eliminated); vsum slice in
//    LDS; softmax exchange via 2 KB double-buffered c_s with raw
//    lgkmcnt(0)+s_barrier (no vmcnt drain -> W prefetch survives the barriers).
//  - reduce_squash vectorized to float4.

#define B_TOT   64
#define IN_CAPS 2048
#define DIN     16
#define NC      32
#define DC      32
#define JD      (NC * DC)            // 1024
#define B_CHUNK 8
#define I_CHUNK 16
#define N_IG    (IN_CAPS / I_CHUNK)  // 128 i-groups
#define N_BG    (B_TOT / B_CHUNK)    // 8 b-groups
#define EPS_SQ  1e-7f

__device__ __forceinline__ float dot4(const float4 a, const float4 b) {
    return a.x*b.x + a.y*b.y + a.z*b.z + a.w*b.w;
}

// Raw workgroup barrier: drain LDS ops only, then s_barrier. Deliberately does
// NOT drain vmcnt, so global W-prefetch loads stay in flight across it.
// Empty memory-clobber asms fence compiler code motion on both sides.
#define LDS_BARRIER() do {                                  \
    asm volatile("" ::: "memory");                          \
    asm volatile("s_waitcnt lgkmcnt(0)");                   \
    __builtin_amdgcn_s_barrier();                           \
    asm volatile("" ::: "memory");                          \
} while (0)

// PHASE 0: c = 1/32 uniform (softmax of zeros), plain sum.
// PHASE 1: logits = hat . vsum, softmax over j, weighted sum.
// ATOMIC 0: write private partial P[ig][b][jd]. ATOMIC 1: atomicAdd into S.
template <int PHASE, int ATOMIC>
__launch_bounds__(256, PHASE == 0 ? 4 : 3)
__global__ void caps_pass(const float* __restrict__ x,
                          const float* __restrict__ W,
                          const float* __restrict__ vsum,
                          float* __restrict__ P)
{
    __shared__ float4 xs4[I_CHUNK][B_CHUNK][DIN / 4];        // 8 KB
    __shared__ float4 vs4[PHASE ? B_CHUNK * (JD / 4) : 1];   // 32 KB (phase 1)
    __shared__ float  c_s[PHASE ? 2 : 1][B_CHUNK][NC];       // 2 KB  (phase 1)

    const int t    = threadIdx.x;           // 256 threads
    const int j    = t >> 3;                // 0..31 output capsule
    const int dq   = t & 7;                 // d-quad 0..7
    const int doff = dq * 4;
    const int jd0  = j * DC + doff;

    // XCD-clustered swizzle (assumes round-robin XCD = linear_id % 8):
    // all 8 bg-siblings of one ig occupy consecutive slots on ONE XCD.
    const int r   = blockIdx.x;             // 0..1023
    const int xcd = r & 7;
    const int s   = r >> 3;                 // 0..127
    const int bg  = s & 7;
    const int ig  = (s >> 3) * 8 + xcd;     // 0..127
    const int b0  = bg * B_CHUNK;
    const int i0  = ig * I_CHUNK;

    // ---- stage x (and vsum) once; W prologue loads issued before LDS stores ----
    float4 sx[2];
    int il_s[2], bl_s[2], k4_s[2];
#pragma unroll
    for (int q = 0; q < 2; ++q) {
        const int f = t * 2 + q;            // 512 float4 total
        il_s[q] = f >> 5;                   // 32 float4 per il
        bl_s[q] = (f >> 2) & 7;
        k4_s[q] = f & 3;
        sx[q] = *(const float4*)
            &x[((size_t)(b0 + bl_s[q]) * IN_CAPS + (i0 + il_s[q])) * DIN + k4_s[q] * 4];
    }
    float4 sv[8];
    if (PHASE) {
#pragma unroll
        for (int q = 0; q < 8; ++q) {
            const int f = q * 256 + t;      // 2048 float4 total
            sv[q] = *(const float4*)&vsum[(size_t)(b0 + (f >> 8)) * JD + (f & 255) * 4];
        }
    }

    // this thread's W slice base: rows (j, doff..doff+3), 16 contiguous float4 per i.
    const float4* Wbase =
        (const float4*)W + (((size_t)j * IN_CAPS + i0) * DC + doff) * (DIN / 4);

    float4 wA[8], wB[8];
#pragma unroll
    for (int q = 0; q < 8; ++q) wA[q] = Wbase[q];   // il=0, rows doff..doff+1

    // LDS stores (compiler waits only the staging loads; wA stays outstanding)
#pragma unroll
    for (int q = 0; q < 2; ++q) xs4[il_s[q]][bl_s[q]][k4_s[q]] = sx[q];
    if (PHASE) {
#pragma unroll
        for (int q = 0; q < 8; ++q) vs4[q * 256 + t] = sv[q];
    }
    LDS_BARRIER();

    float acc[B_CHUNK][4];
#pragma unroll
    for (int b = 0; b < B_CHUNK; ++b)
#pragma unroll
        for (int dd = 0; dd < 4; ++dd) acc[b][dd] = 0.f;

    float h[B_CHUNK][4];   // phase-1 hat fragments (registers, not LDS)
    int buf = 0;

    for (int il = 0; il < I_CHUNK; ++il) {
        const float4* Wc = Wbase + (size_t)il * (DC * DIN / 4);

        // prefetch second half of this il (rows doff+2, doff+3)
#pragma unroll
        for (int q = 0; q < 8; ++q) wB[q] = Wc[8 + q];

        // compute half 0 from wA
#pragma unroll
        for (int b = 0; b < B_CHUNK; ++b) {
            float s0 = 0.f, s1 = 0.f;
#pragma unroll
            for (int k4 = 0; k4 < 4; ++k4) {
                const float4 xv = xs4[il][b][k4];   // broadcast read
                s0 += dot4(wA[k4],     xv);
                s1 += dot4(wA[4 + k4], xv);
            }
            if (PHASE == 0) { acc[b][0] += s0; acc[b][1] += s1; }
            else            { h[b][0] = s0;    h[b][1] = s1; }
        }

        // prefetch first half of NEXT il (stays in flight across phase-1 barriers)
        if (il < I_CHUNK - 1) {
#pragma unroll
            for (int q = 0; q < 8; ++q) wA[q] = Wc[(DC * DIN / 4) + q];
        }

        // compute half 1 from wB
#pragma unroll
        for (int b = 0; b < B_CHUNK; ++b) {
            float s2 = 0.f, s3 = 0.f;
#pragma unroll
            for (int k4 = 0; k4 < 4; ++k4) {
                const float4 xv = xs4[il][b][k4];
                s2 += dot4(wB[k4],     xv);
                s3 += dot4(wB[4 + k4], xv);
            }
            if (PHASE == 0) { acc[b][2] += s2; acc[b][3] += s3; }
            else            { h[b][2] = s2;    h[b][3] = s3; }
        }

        if (PHASE == 1) {
            // logits: lp[b] = hat[b] . vsum[b] over this thread's 4 d's,
            // then reduce over the 8 dq-threads sharing j (full d coverage).
            float lp[B_CHUNK];
#pragma unroll
            for (int b = 0; b < B_CHUNK; ++b) {
                const float4 vv = vs4[b * 256 + j * 8 + dq];   // contiguous: no conflict
                lp[b] = h[b][0]*vv.x + h[b][1]*vv.y + h[b][2]*vv.z + h[b][3]*vv.w;
                lp[b] += __shfl_xor(lp[b], 1, 8);
                lp[b] += __shfl_xor(lp[b], 2, 8);
                lp[b] += __shfl_xor(lp[b], 4, 8);
            }
            if (dq == 0) {
#pragma unroll
                for (int b = 0; b < B_CHUNK; ++b) c_s[buf][b][j] = lp[b];
            }
            LDS_BARRIER();

            // softmax over j: one thread per (b, j); width-32 butterflies.
            {
                const int tb = t >> 5, tj = t & 31;
                const float l = c_s[buf][tb][tj];
                float m = l;
                m = fmaxf(m, __shfl_xor(m, 1, 32));
                m = fmaxf(m, __shfl_xor(m, 2, 32));
                m = fmaxf(m, __shfl_xor(m, 4, 32));
                m = fmaxf(m, __shfl_xor(m, 8, 32));
                m = fmaxf(m, __shfl_xor(m, 16, 32));
                const float e = __expf(l - m);
                float ss = e;
                ss += __shfl_xor(ss, 1, 32);
                ss += __shfl_xor(ss, 2, 32);
                ss += __shfl_xor(ss, 4, 32);
                ss += __shfl_xor(ss, 8, 32);
                ss += __shfl_xor(ss, 16, 32);
                c_s[buf][tb][tj] = e / ss;
            }
            LDS_BARRIER();

            // weighted accumulate from register-held hat
#pragma unroll
            for (int b = 0; b < B_CHUNK; ++b) {
                const float c = c_s[buf][b][j];    // broadcast read
                acc[b][0] += c * h[b][0];
                acc[b][1] += c * h[b][1];
                acc[b][2] += c * h[b][2];
                acc[b][3] += c * h[b][3];
            }
            buf ^= 1;   // next il writes the other c_s buffer: no WAR barrier needed
        }
    }

    const float scale = (PHASE == 0) ? (1.f / NC) : 1.f;
    if (ATOMIC) {
#pragma unroll
        for (int b = 0; b < B_CHUNK; ++b) {
            float* dst = &P[(size_t)(b0 + b) * JD + jd0];
            atomicAdd(dst + 0, acc[b][0] * scale);
            atomicAdd(dst + 1, acc[b][1] * scale);
            atomicAdd(dst + 2, acc[b][2] * scale);
            atomicAdd(dst + 3, acc[b][3] * scale);
        }
    } else {
        // private partial: P[ig][b_global][jd], coalesced float4 stores
        float* dst = P + ((size_t)ig * B_TOT + b0) * JD + jd0;
#pragma unroll
        for (int b = 0; b < B_CHUNK; ++b) {
            *(float4*)(dst + (size_t)b * JD) =
                make_float4(acc[b][0] * scale, acc[b][1] * scale,
                            acc[b][2] * scale, acc[b][3] * scale);
        }
    }
}

// Sum nparts partials (float4), squash over Dc=32 (8 consecutive lanes = one
// capsule), then: mode 0: VSUM = v ; mode 1: VSUM += v ; mode 2: OUT = v
__global__ void reduce_squash(const float* __restrict__ Pf, int nparts,
                              float* __restrict__ VSUMf,
                              float* __restrict__ OUTf, int mode)
{
    const float4* P4   = (const float4*)Pf;
    float4* VSUM       = (float4*)VSUMf;
    float4* OUT        = (float4*)OUTf;
    const int idx = blockIdx.x * blockDim.x + threadIdx.x;   // 0..16383
    float4 v = make_float4(0.f, 0.f, 0.f, 0.f);
#pragma unroll 8
    for (int ig = 0; ig < nparts; ++ig) {
        const float4 p = P4[(size_t)ig * (B_TOT * JD / 4) + idx];
        v.x += p.x; v.y += p.y; v.z += p.z; v.w += p.w;
    }
    float s2 = v.x*v.x + v.y*v.y + v.z*v.z + v.w*v.w;
    s2 += __shfl_xor(s2, 1, 8);
    s2 += __shfl_xor(s2, 2, 8);
    s2 += __shfl_xor(s2, 4, 8);
    const float sc = s2 / (1.f + s2) * rsqrtf(s2 + EPS_SQ);
    float4 o = make_float4(v.x * sc, v.y * sc, v.z * sc, v.w * sc);
    if (mode == 0) {
        VSUM[idx] = o;
    } else if (mode == 1) {
        float4 u = VSUM[idx];
        u.x += o.x; u.y += o.y; u.z += o.z; u.w += o.w;
        VSUM[idx] = u;
    } else {
        OUT[idx] = o;
    }
}

extern "C" void kernel_launch(void* const* d_in, const int* in_sizes, int n_in,
                              void* d_out, int out_size, void* d_ws, size_t ws_size,
                              hipStream_t stream)
{
    const float* x = (const float*)d_in[0];   // [64, 2048, 16]
    const float* W = (const float*)d_in[1];   // [32, 2048, 32, 16]
    float* out = (float*)d_out;               // [64, 32, 32]

    const dim3 grid(N_IG * N_BG);             // 1024 blocks (XCD-swizzled in-kernel)
    const dim3 blk(256);
    const dim3 rgrid(B_TOT * JD / 4 / 256);   // 64 blocks

    const size_t P_elems = (size_t)N_IG * B_TOT * JD;   // 8.4M floats = 33.6 MB
    const size_t need    = (P_elems + (size_t)B_TOT * JD) * sizeof(float);

    if (ws_size >= need) {
        // partial-sum path (no atomics, no memsets)
        float* P    = (float*)d_ws;
        float* VSUM = P + P_elems;
        caps_pass<0, 0><<<grid, blk, 0, stream>>>(x, W, nullptr, P);
        reduce_squash<<<rgrid, blk, 0, stream>>>(P, N_IG, VSUM, out, 0);
        caps_pass<1, 0><<<grid, blk, 0, stream>>>(x, W, VSUM, P);
        reduce_squash<<<rgrid, blk, 0, stream>>>(P, N_IG, VSUM, out, 1);
        caps_pass<1, 0><<<grid, blk, 0, stream>>>(x, W, VSUM, P);
        reduce_squash<<<rgrid, blk, 0, stream>>>(P, N_IG, VSUM, out, 2);
    } else {
        // atomic fallback
        float* S    = (float*)d_ws;
        float* VSUM = S + (size_t)B_TOT * JD;
        const size_t sbytes = (size_t)B_TOT * JD * sizeof(float);
        hipMemsetAsync(S, 0, sbytes, stream);
        caps_pass<0, 1><<<grid, blk, 0, stream>>>(x, W, nullptr, S);
        reduce_squash<<<rgrid, blk, 0, stream>>>(S, 1, VSUM, out, 0);
        hipMemsetAsync(S, 0, sbytes, stream);
        caps_pass<1, 1><<<grid, blk, 0, stream>>>(x, W, VSUM, S);
        reduce_squash<<<rgrid, blk, 0, stream>>>(S, 1, VSUM, out, 1);
        hipMemsetAsync(S, 0, sbytes, stream);
        caps_pass<1, 1><<<grid, blk, 0, stream>>>(x, W, VSUM, S);
        reduce_squash<<<rgrid, blk, 0, stream>>>(S, 1, VSUM, out, 2);
    }
}

// Round 2
// 1066.127 us; speedup vs baseline: 3.3547x; 3.3547x over previous
//
#include <hip/hip_runtime.h>
#include <math.h>

// CapsuleLayer dynamic routing, MI355X fp32. Round 4: fix round-3 spill.
// B=64, In=2048, Din=16, Nc=32, Dc=32, ROUTINGS=3.
// Identity: b starts at 0 => logits_t = hat . (v1+..+v_{t-1}); never store b or hat.
//
// Round-3 post-mortem: __launch_bounds__(256,4) capped VGPR at 128; kernel needs
// ~140 -> allocator spilled to scratch (VGPR=64, FETCH 1.8GB, WRITE 3.2GB/dispatch,
// phase-0 325us -> 1716us). Fix: cap at 256 via (256,2) on BOTH phases. Structure
// unchanged from round 3:
//  - B_CHUNK 8, grid 1024 blocks, XCD-clustered swizzle (8 bg-siblings of an
//    i-group back-to-back on one XCD -> W slice shared in that XCD's L2).
//  - x staged fully up front (8 KB LDS, ONE barrier). Phase 0: zero barriers in
//    the il loop; W double-buffered in half-il register chunks (wA/wB).
//  - Phase 1: hat in REGISTERS (no 64 KB hat_s); vsum slice in LDS; softmax
//    exchange via 2 KB double-buffered c_s with raw lgkmcnt(0)+s_barrier (no
//    vmcnt drain -> W prefetch survives the barriers).

#define B_TOT   64
#define IN_CAPS 2048
#define DIN     16
#define NC      32
#define DC      32
#define JD      (NC * DC)            // 1024
#define B_CHUNK 8
#define I_CHUNK 16
#define N_IG    (IN_CAPS / I_CHUNK)  // 128 i-groups
#define N_BG    (B_TOT / B_CHUNK)    // 8 b-groups
#define EPS_SQ  1e-7f

__device__ __forceinline__ float dot4(const float4 a, const float4 b) {
    return a.x*b.x + a.y*b.y + a.z*b.z + a.w*b.w;
}

// Raw workgroup barrier: drain LDS ops only, then s_barrier. Deliberately does
// NOT drain vmcnt, so global W-prefetch loads stay in flight across it.
#define LDS_BARRIER() do {                                  \
    asm volatile("" ::: "memory");                          \
    asm volatile("s_waitcnt lgkmcnt(0)");                   \
    __builtin_amdgcn_s_barrier();                           \
    asm volatile("" ::: "memory");                          \
} while (0)

// PHASE 0: c = 1/32 uniform (softmax of zeros), plain sum.
// PHASE 1: logits = hat . vsum, softmax over j, weighted sum.
// ATOMIC 0: write private partial P[ig][b][jd]. ATOMIC 1: atomicAdd into S.
template <int PHASE, int ATOMIC>
__launch_bounds__(256, 2)   // VGPR cap 256: round-3's (256,4) cap of 128 spilled
__global__ void caps_pass(const float* __restrict__ x,
                          const float* __restrict__ W,
                          const float* __restrict__ vsum,
                          float* __restrict__ P)
{
    __shared__ float4 xs4[I_CHUNK][B_CHUNK][DIN / 4];        // 8 KB
    __shared__ float4 vs4[PHASE ? B_CHUNK * (JD / 4) : 1];   // 32 KB (phase 1)
    __shared__ float  c_s[PHASE ? 2 : 1][B_CHUNK][NC];       // 2 KB  (phase 1)

    const int t    = threadIdx.x;           // 256 threads
    const int j    = t >> 3;                // 0..31 output capsule
    const int dq   = t & 7;                 // d-quad 0..7
    const int doff = dq * 4;
    const int jd0  = j * DC + doff;

    // XCD-clustered swizzle (round-robin XCD = linear_id % 8):
    // all 8 bg-siblings of one ig occupy consecutive slots on ONE XCD.
    const int r   = blockIdx.x;             // 0..1023
    const int xcd = r & 7;
    const int s   = r >> 3;                 // 0..127
    const int bg  = s & 7;
    const int ig  = (s >> 3) * 8 + xcd;     // 0..127
    const int b0  = bg * B_CHUNK;
    const int i0  = ig * I_CHUNK;

    // ---- stage x (and vsum) once; W prologue loads issued before LDS stores ----
    float4 sx[2];
    int il_s[2], bl_s[2], k4_s[2];
#pragma unroll
    for (int q = 0; q < 2; ++q) {
        const int f = t * 2 + q;            // 512 float4 total
        il_s[q] = f >> 5;                   // 32 float4 per il
        bl_s[q] = (f >> 2) & 7;
        k4_s[q] = f & 3;
        sx[q] = *(const float4*)
            &x[((size_t)(b0 + bl_s[q]) * IN_CAPS + (i0 + il_s[q])) * DIN + k4_s[q] * 4];
    }
    float4 sv[8];
    if (PHASE) {
#pragma unroll
        for (int q = 0; q < 8; ++q) {
            const int f = q * 256 + t;      // 2048 float4 total
            sv[q] = *(const float4*)&vsum[(size_t)(b0 + (f >> 8)) * JD + (f & 255) * 4];
        }
    }

    // this thread's W slice base: rows (j, doff..doff+3), 16 contiguous float4 per i.
    const float4* Wbase =
        (const float4*)W + (((size_t)j * IN_CAPS + i0) * DC + doff) * (DIN / 4);

    float4 wA[8], wB[8];
#pragma unroll
    for (int q = 0; q < 8; ++q) wA[q] = Wbase[q];   // il=0, rows doff..doff+1

    // LDS stores (compiler waits only the staging loads; wA stays outstanding)
#pragma unroll
    for (int q = 0; q < 2; ++q) xs4[il_s[q]][bl_s[q]][k4_s[q]] = sx[q];
    if (PHASE) {
#pragma unroll
        for (int q = 0; q < 8; ++q) vs4[q * 256 + t] = sv[q];
    }
    LDS_BARRIER();

    float acc[B_CHUNK][4];
#pragma unroll
    for (int b = 0; b < B_CHUNK; ++b)
#pragma unroll
        for (int dd = 0; dd < 4; ++dd) acc[b][dd] = 0.f;

    float h[B_CHUNK][4];   // phase-1 hat fragments (registers, not LDS)
    int buf = 0;

    for (int il = 0; il < I_CHUNK; ++il) {
        const float4* Wc = Wbase + (size_t)il * (DC * DIN / 4);

        // prefetch second half of this il (rows doff+2, doff+3)
#pragma unroll
        for (int q = 0; q < 8; ++q) wB[q] = Wc[8 + q];

        // compute half 0 from wA
#pragma unroll
        for (int b = 0; b < B_CHUNK; ++b) {
            float s0 = 0.f, s1 = 0.f;
#pragma unroll
            for (int k4 = 0; k4 < 4; ++k4) {
                const float4 xv = xs4[il][b][k4];   // broadcast read
                s0 += dot4(wA[k4],     xv);
                s1 += dot4(wA[4 + k4], xv);
            }
            if (PHASE == 0) { acc[b][0] += s0; acc[b][1] += s1; }
            else            { h[b][0] = s0;    h[b][1] = s1; }
        }

        // prefetch first half of NEXT il (stays in flight across phase-1 barriers)
        if (il < I_CHUNK - 1) {
#pragma unroll
            for (int q = 0; q < 8; ++q) wA[q] = Wc[(DC * DIN / 4) + q];
        }

        // compute half 1 from wB
#pragma unroll
        for (int b = 0; b < B_CHUNK; ++b) {
            float s2 = 0.f, s3 = 0.f;
#pragma unroll
            for (int k4 = 0; k4 < 4; ++k4) {
                const float4 xv = xs4[il][b][k4];
                s2 += dot4(wB[k4],     xv);
                s3 += dot4(wB[4 + k4], xv);
            }
            if (PHASE == 0) { acc[b][2] += s2; acc[b][3] += s3; }
            else            { h[b][2] = s2;    h[b][3] = s3; }
        }

        if (PHASE == 1) {
            // logits: lp[b] = hat[b] . vsum[b] over this thread's 4 d's,
            // then reduce over the 8 dq-threads sharing j (full d coverage).
            float lp[B_CHUNK];
#pragma unroll
            for (int b = 0; b < B_CHUNK; ++b) {
                const float4 vv = vs4[b * 256 + j * 8 + dq];   // contiguous: no conflict
                lp[b] = h[b][0]*vv.x + h[b][1]*vv.y + h[b][2]*vv.z + h[b][3]*vv.w;
                lp[b] += __shfl_xor(lp[b], 1, 8);
                lp[b] += __shfl_xor(lp[b], 2, 8);
                lp[b] += __shfl_xor(lp[b], 4, 8);
            }
            if (dq == 0) {
#pragma unroll
                for (int b = 0; b < B_CHUNK; ++b) c_s[buf][b][j] = lp[b];
            }
            LDS_BARRIER();

            // softmax over j: one thread per (b, j); width-32 butterflies.
            {
                const int tb = t >> 5, tj = t & 31;
                const float l = c_s[buf][tb][tj];
                float m = l;
                m = fmaxf(m, __shfl_xor(m, 1, 32));
                m = fmaxf(m, __shfl_xor(m, 2, 32));
                m = fmaxf(m, __shfl_xor(m, 4, 32));
                m = fmaxf(m, __shfl_xor(m, 8, 32));
                m = fmaxf(m, __shfl_xor(m, 16, 32));
                const float e = __expf(l - m);
                float ss = e;
                ss += __shfl_xor(ss, 1, 32);
                ss += __shfl_xor(ss, 2, 32);
                ss += __shfl_xor(ss, 4, 32);
                ss += __shfl_xor(ss, 8, 32);
                ss += __shfl_xor(ss, 16, 32);
                c_s[buf][tb][tj] = e / ss;
            }
            LDS_BARRIER();

            // weighted accumulate from register-held hat
#pragma unroll
            for (int b = 0; b < B_CHUNK; ++b) {
                const float c = c_s[buf][b][j];    // broadcast read
                acc[b][0] += c * h[b][0];
                acc[b][1] += c * h[b][1];
                acc[b][2] += c * h[b][2];
                acc[b][3] += c * h[b][3];
            }
            buf ^= 1;   // next il writes the other c_s buffer: no WAR barrier needed
        }
    }

    const float scale = (PHASE == 0) ? (1.f / NC) : 1.f;
    if (ATOMIC) {
#pragma unroll
        for (int b = 0; b < B_CHUNK; ++b) {
            float* dst = &P[(size_t)(b0 + b) * JD + jd0];
            atomicAdd(dst + 0, acc[b][0] * scale);
            atomicAdd(dst + 1, acc[b][1] * scale);
            atomicAdd(dst + 2, acc[b][2] * scale);
            atomicAdd(dst + 3, acc[b][3] * scale);
        }
    } else {
        // private partial: P[ig][b_global][jd], coalesced float4 stores
        float* dst = P + ((size_t)ig * B_TOT + b0) * JD + jd0;
#pragma unroll
        for (int b = 0; b < B_CHUNK; ++b) {
            *(float4*)(dst + (size_t)b * JD) =
                make_float4(acc[b][0] * scale, acc[b][1] * scale,
                            acc[b][2] * scale, acc[b][3] * scale);
        }
    }
}

// Sum nparts partials (float4), squash over Dc=32 (8 consecutive lanes = one
// capsule), then: mode 0: VSUM = v ; mode 1: VSUM += v ; mode 2: OUT = v
__global__ void reduce_squash(const float* __restrict__ Pf, int nparts,
                              float* __restrict__ VSUMf,
                              float* __restrict__ OUTf, int mode)
{
    const float4* P4   = (const float4*)Pf;
    float4* VSUM       = (float4*)VSUMf;
    float4* OUT        = (float4*)OUTf;
    const int idx = blockIdx.x * blockDim.x + threadIdx.x;   // 0..16383
    float4 v = make_float4(0.f, 0.f, 0.f, 0.f);
#pragma unroll 8
    for (int ig = 0; ig < nparts; ++ig) {
        const float4 p = P4[(size_t)ig * (B_TOT * JD / 4) + idx];
        v.x += p.x; v.y += p.y; v.z += p.z; v.w += p.w;
    }
    float s2 = v.x*v.x + v.y*v.y + v.z*v.z + v.w*v.w;
    s2 += __shfl_xor(s2, 1, 8);
    s2 += __shfl_xor(s2, 2, 8);
    s2 += __shfl_xor(s2, 4, 8);
    const float sc = s2 / (1.f + s2) * rsqrtf(s2 + EPS_SQ);
    float4 o = make_float4(v.x * sc, v.y * sc, v.z * sc, v.w * sc);
    if (mode == 0) {
        VSUM[idx] = o;
    } else if (mode == 1) {
        float4 u = VSUM[idx];
        u.x += o.x; u.y += o.y; u.z += o.z; u.w += o.w;
        VSUM[idx] = u;
    } else {
        OUT[idx] = o;
    }
}

extern "C" void kernel_launch(void* const* d_in, const int* in_sizes, int n_in,
                              void* d_out, int out_size, void* d_ws, size_t ws_size,
                              hipStream_t stream)
{
    const float* x = (const float*)d_in[0];   // [64, 2048, 16]
    const float* W = (const float*)d_in[1];   // [32, 2048, 32, 16]
    float* out = (float*)d_out;               // [64, 32, 32]

    const dim3 grid(N_IG * N_BG);             // 1024 blocks (XCD-swizzled in-kernel)
    const dim3 blk(256);
    const dim3 rgrid(B_TOT * JD / 4 / 256);   // 64 blocks

    const size_t P_elems = (size_t)N_IG * B_TOT * JD;   // 8.4M floats = 33.6 MB
    const size_t need    = (P_elems + (size_t)B_TOT * JD) * sizeof(float);

    if (ws_size >= need) {
        // partial-sum path (no atomics, no memsets)
        float* P    = (float*)d_ws;
        float* VSUM = P + P_elems;
        caps_pass<0, 0><<<grid, blk, 0, stream>>>(x, W, nullptr, P);
        reduce_squash<<<rgrid, blk, 0, stream>>>(P, N_IG, VSUM, out, 0);
        caps_pass<1, 0><<<grid, blk, 0, stream>>>(x, W, VSUM, P);
        reduce_squash<<<rgrid, blk, 0, stream>>>(P, N_IG, VSUM, out, 1);
        caps_pass<1, 0><<<grid, blk, 0, stream>>>(x, W, VSUM, P);
        reduce_squash<<<rgrid, blk, 0, stream>>>(P, N_IG, VSUM, out, 2);
    } else {
        // atomic fallback
        float* S    = (float*)d_ws;
        float* VSUM = S + (size_t)B_TOT * JD;
        const size_t sbytes = (size_t)B_TOT * JD * sizeof(float);
        hipMemsetAsync(S, 0, sbytes, stream);
        caps_pass<0, 1><<<grid, blk, 0, stream>>>(x, W, nullptr, S);
        reduce_squash<<<rgrid, blk, 0, stream>>>(S, 1, VSUM, out, 0);
        hipMemsetAsync(S, 0, sbytes, stream);
        caps_pass<1, 1><<<grid, blk, 0, stream>>>(x, W, VSUM, S);
        reduce_squash<<<rgrid, blk, 0, stream>>>(S, 1, VSUM, out, 1);
        hipMemsetAsync(S, 0, sbytes, stream);
        caps_pass<1, 1><<<grid, blk, 0, stream>>>(x, W, VSUM, S);
        reduce_squash<<<rgrid, blk, 0, stream>>>(S, 1, VSUM, out, 2);
    }
}

// Round 3
// 746.998 us; speedup vs baseline: 4.7878x; 1.4272x over previous
//
#include <hip/hip_runtime.h>
#include <math.h>

// CapsuleLayer dynamic routing, MI355X fp32. Round 5: register diet (kill spills).
// B=64, In=2048, Din=16, Nc=32, Dc=32, ROUTINGS=3.
// Identity: b starts at 0 => logits_t = hat . (v1+..+v_{t-1}); never store b or hat.
//
// Round-4 post-mortem: WRITE_SIZE 648MB/dispatch vs 33.6MB of real writes =
// ~600MB scratch spill traffic (wA/wB=64 + acc/h=64 + staging > the 128 VGPRs
// the allocator settles on). Every prior round spilled (baseline: 330MB writes).
// Fix: true demand < 128.
//  - W buffering: k-quarter double-buffer (wE[4]/wO[4] = 32 VGPR, was 64).
//    Quarter = all 4 d-rows at one k4; h/acc accumulate across quarters in the
//    same FP order as before. xs4 read once per (b,k4), broadcast, conflict-free.
//  - Phase 1: vs4 LDS (32KB) dropped; vsum read from global per il (256KB total,
//    L1/L2-resident, coalesced 16B/lane). Phase-1 LDS 42KB -> 10KB.
//  - Register budget: phase 0 ~76, phase 1 ~116. Grid 1024 = 4 blocks/CU, all
//    resident in one generation, 16 waves/CU.
//  - Kept: XCD-clustered swizzle, x staged up front (one barrier), raw
//    lgkmcnt-only barriers (W prefetch survives them), hat in registers.

#define B_TOT   64
#define IN_CAPS 2048
#define DIN     16
#define NC      32
#define DC      32
#define JD      (NC * DC)            // 1024
#define B_CHUNK 8
#define I_CHUNK 16
#define N_IG    (IN_CAPS / I_CHUNK)  // 128 i-groups
#define N_BG    (B_TOT / B_CHUNK)    // 8 b-groups
#define EPS_SQ  1e-7f

__device__ __forceinline__ float dot4(const float4 a, const float4 b) {
    return a.x*b.x + a.y*b.y + a.z*b.z + a.w*b.w;
}

// Raw workgroup barrier: drain LDS ops only, then s_barrier. Deliberately does
// NOT drain vmcnt, so global W-prefetch loads stay in flight across it.
#define LDS_BARRIER() do {                                  \
    asm volatile("" ::: "memory");                          \
    asm volatile("s_waitcnt lgkmcnt(0)");                   \
    __builtin_amdgcn_s_barrier();                           \
    asm volatile("" ::: "memory");                          \
} while (0)

// Load one k-quarter: rows doff..doff+3 at fixed k4 of input capsule (i0+il).
// Quad index for (il, d, k4) = il*128 + d*4 + k4; row stride = 4 quads (64B).
__device__ __forceinline__ void wload(float4 (&w)[4], const float4* __restrict__ Wq,
                                      int il, int k4, int doff) {
    const float4* p = Wq + (size_t)il * (DC * DIN / 4) + doff * 4 + k4;
    w[0] = p[0];
    w[1] = p[4];
    w[2] = p[8];
    w[3] = p[12];
}

// One quarter of compute: dst[b][r] (+)= dot(W[row doff+r, k4-quad], x[b, k4-quad])
template <bool ACCUM>
__device__ __forceinline__ void qcomp(const float4 (&w)[4],
                                      const float4 (*__restrict__ xsil)[DIN / 4],
                                      int k4, float (*__restrict__ dst)[4]) {
#pragma unroll
    for (int b = 0; b < B_CHUNK; ++b) {
        const float4 xv = xsil[b][k4];     // block-uniform: LDS broadcast
        if (ACCUM) {
            dst[b][0] += dot4(w[0], xv);
            dst[b][1] += dot4(w[1], xv);
            dst[b][2] += dot4(w[2], xv);
            dst[b][3] += dot4(w[3], xv);
        } else {
            dst[b][0] = dot4(w[0], xv);
            dst[b][1] = dot4(w[1], xv);
            dst[b][2] = dot4(w[2], xv);
            dst[b][3] = dot4(w[3], xv);
        }
    }
}

// PHASE 0: c = 1/32 uniform (softmax of zeros), plain sum.
// PHASE 1: logits = hat . vsum, softmax over j, weighted sum.
// ATOMIC 0: write private partial P[ig][b][jd]. ATOMIC 1: atomicAdd into S.
template <int PHASE, int ATOMIC>
__launch_bounds__(256, 2)
__global__ void caps_pass(const float* __restrict__ x,
                          const float* __restrict__ W,
                          const float* __restrict__ vsum,
                          float* __restrict__ P)
{
    __shared__ float4 xs4[I_CHUNK][B_CHUNK][DIN / 4];        // 8 KB
    __shared__ float  c_s[PHASE ? 2 : 1][B_CHUNK][NC];       // 2 KB (phase 1)

    const int t    = threadIdx.x;           // 256 threads
    const int j    = t >> 3;                // 0..31 output capsule
    const int dq   = t & 7;                 // d-quad 0..7
    const int doff = dq * 4;
    const int jd0  = j * DC + doff;

    // XCD-clustered swizzle (round-robin XCD = linear_id % 8):
    // all 8 bg-siblings of one ig occupy consecutive slots on ONE XCD.
    const int r   = blockIdx.x;             // 0..1023
    const int xcd = r & 7;
    const int s   = r >> 3;                 // 0..127
    const int bg  = s & 7;
    const int ig  = (s >> 3) * 8 + xcd;     // 0..127
    const int b0  = bg * B_CHUNK;
    const int i0  = ig * I_CHUNK;

    // ---- stage x once (sx loads issued BEFORE the W prologue load so the
    //      ds_write's vmcnt wait does not drain the W quads) ----
    float4 sx[2];
    int il_s[2], bl_s[2], k4_s[2];
#pragma unroll
    for (int q = 0; q < 2; ++q) {
        const int f = t * 2 + q;            // 512 float4 total
        il_s[q] = f >> 5;                   // 32 float4 per il
        bl_s[q] = (f >> 2) & 7;
        k4_s[q] = f & 3;
        sx[q] = *(const float4*)
            &x[((size_t)(b0 + bl_s[q]) * IN_CAPS + (i0 + il_s[q])) * DIN + k4_s[q] * 4];
    }

    // W slice base for this thread's (j, rows doff..doff+3)
    const float4* Wq =
        (const float4*)W + ((size_t)j * IN_CAPS + i0) * DC * (DIN / 4);

    float4 wE[4], wO[4];
    wload(wE, Wq, 0, 0, doff);              // prologue: quarter (il=0, k4=0)

#pragma unroll
    for (int q = 0; q < 2; ++q) xs4[il_s[q]][bl_s[q]][k4_s[q]] = sx[q];
    LDS_BARRIER();

    float acc[B_CHUNK][4];
#pragma unroll
    for (int b = 0; b < B_CHUNK; ++b)
#pragma unroll
        for (int dd = 0; dd < 4; ++dd) acc[b][dd] = 0.f;

    float h[B_CHUNK][4];   // phase-1 hat fragments (registers); dead in phase 0
    int buf = 0;

#pragma unroll 1
    for (int il = 0; il < I_CHUNK; ++il) {
        const float4 (*__restrict__ xsil)[DIN / 4] = xs4[il];
        float (*dst)[4] = PHASE ? h : acc;

        // 4 k-quarters, wE/wO ping-pong; next quarter's load issued before the
        // current quarter's compute.
        wload(wO, Wq, il, 1, doff);
        if (PHASE == 0) qcomp<true >(wE, xsil, 0, acc);
        else            qcomp<false>(wE, xsil, 0, h);
        wload(wE, Wq, il, 2, doff);
        qcomp<true>(wO, xsil, 1, dst);
        wload(wO, Wq, il, 3, doff);
        qcomp<true>(wE, xsil, 2, dst);
        if (il + 1 < I_CHUNK) wload(wE, Wq, il + 1, 0, doff);
        qcomp<true>(wO, xsil, 3, dst);

        if (PHASE == 1) {
            // logits: lp[b] = hat[b] . vsum[b] over this thread's 4 d's (vsum
            // straight from global: 16B/lane coalesced, L1/L2-resident),
            // then reduce over the 8 dq-threads sharing j.
            float lp[B_CHUNK];
#pragma unroll
            for (int b = 0; b < B_CHUNK; ++b) {
                const float4 vv =
                    *(const float4*)&vsum[(size_t)(b0 + b) * JD + jd0];
                lp[b] = h[b][0]*vv.x + h[b][1]*vv.y + h[b][2]*vv.z + h[b][3]*vv.w;
                lp[b] += __shfl_xor(lp[b], 1, 8);
                lp[b] += __shfl_xor(lp[b], 2, 8);
                lp[b] += __shfl_xor(lp[b], 4, 8);
            }
            if (dq == 0) {
#pragma unroll
                for (int b = 0; b < B_CHUNK; ++b) c_s[buf][b][j] = lp[b];
            }
            LDS_BARRIER();

            // softmax over j: one thread per (b, j); width-32 butterflies.
            {
                const int tb = t >> 5, tj = t & 31;
                const float l = c_s[buf][tb][tj];
                float m = l;
                m = fmaxf(m, __shfl_xor(m, 1, 32));
                m = fmaxf(m, __shfl_xor(m, 2, 32));
                m = fmaxf(m, __shfl_xor(m, 4, 32));
                m = fmaxf(m, __shfl_xor(m, 8, 32));
                m = fmaxf(m, __shfl_xor(m, 16, 32));
                const float e = __expf(l - m);
                float ss = e;
                ss += __shfl_xor(ss, 1, 32);
                ss += __shfl_xor(ss, 2, 32);
                ss += __shfl_xor(ss, 4, 32);
                ss += __shfl_xor(ss, 8, 32);
                ss += __shfl_xor(ss, 16, 32);
                c_s[buf][tb][tj] = e / ss;
            }
            LDS_BARRIER();

            // weighted accumulate from register-held hat
#pragma unroll
            for (int b = 0; b < B_CHUNK; ++b) {
                const float c = c_s[buf][b][j];    // broadcast read
                acc[b][0] += c * h[b][0];
                acc[b][1] += c * h[b][1];
                acc[b][2] += c * h[b][2];
                acc[b][3] += c * h[b][3];
            }
            buf ^= 1;   // next il writes the other c_s buffer: no WAR barrier needed
        }
    }

    const float scale = (PHASE == 0) ? (1.f / NC) : 1.f;
    if (ATOMIC) {
#pragma unroll
        for (int b = 0; b < B_CHUNK; ++b) {
            float* dstp = &P[(size_t)(b0 + b) * JD + jd0];
            atomicAdd(dstp + 0, acc[b][0] * scale);
            atomicAdd(dstp + 1, acc[b][1] * scale);
            atomicAdd(dstp + 2, acc[b][2] * scale);
            atomicAdd(dstp + 3, acc[b][3] * scale);
        }
    } else {
        // private partial: P[ig][b_global][jd], coalesced float4 stores
        float* dstp = P + ((size_t)ig * B_TOT + b0) * JD + jd0;
#pragma unroll
        for (int b = 0; b < B_CHUNK; ++b) {
            *(float4*)(dstp + (size_t)b * JD) =
                make_float4(acc[b][0] * scale, acc[b][1] * scale,
                            acc[b][2] * scale, acc[b][3] * scale);
        }
    }
}

// Sum nparts partials (float4), squash over Dc=32 (8 consecutive lanes = one
// capsule), then: mode 0: VSUM = v ; mode 1: VSUM += v ; mode 2: OUT = v
__global__ void reduce_squash(const float* __restrict__ Pf, int nparts,
                              float* __restrict__ VSUMf,
                              float* __restrict__ OUTf, int mode)
{
    const float4* P4   = (const float4*)Pf;
    float4* VSUM       = (float4*)VSUMf;
    float4* OUT        = (float4*)OUTf;
    const int idx = blockIdx.x * blockDim.x + threadIdx.x;   // 0..16383
    float4 v = make_float4(0.f, 0.f, 0.f, 0.f);
#pragma unroll 8
    for (int ig = 0; ig < nparts; ++ig) {
        const float4 p = P4[(size_t)ig * (B_TOT * JD / 4) + idx];
        v.x += p.x; v.y += p.y; v.z += p.z; v.w += p.w;
    }
    float s2 = v.x*v.x + v.y*v.y + v.z*v.z + v.w*v.w;
    s2 += __shfl_xor(s2, 1, 8);
    s2 += __shfl_xor(s2, 2, 8);
    s2 += __shfl_xor(s2, 4, 8);
    const float sc = s2 / (1.f + s2) * rsqrtf(s2 + EPS_SQ);
    float4 o = make_float4(v.x * sc, v.y * sc, v.z * sc, v.w * sc);
    if (mode == 0) {
        VSUM[idx] = o;
    } else if (mode == 1) {
        float4 u = VSUM[idx];
        u.x += o.x; u.y += o.y; u.z += o.z; u.w += o.w;
        VSUM[idx] = u;
    } else {
        OUT[idx] = o;
    }
}

extern "C" void kernel_launch(void* const* d_in, const int* in_sizes, int n_in,
                              void* d_out, int out_size, void* d_ws, size_t ws_size,
                              hipStream_t stream)
{
    const float* x = (const float*)d_in[0];   // [64, 2048, 16]
    const float* W = (const float*)d_in[1];   // [32, 2048, 32, 16]
    float* out = (float*)d_out;               // [64, 32, 32]

    const dim3 grid(N_IG * N_BG);             // 1024 blocks (XCD-swizzled in-kernel)
    const dim3 blk(256);
    const dim3 rgrid(B_TOT * JD / 4 / 256);   // 64 blocks

    const size_t P_elems = (size_t)N_IG * B_TOT * JD;   // 8.4M floats = 33.6 MB
    const size_t need    = (P_elems + (size_t)B_TOT * JD) * sizeof(float);

    if (ws_size >= need) {
        // partial-sum path (no atomics, no memsets)
        float* P    = (float*)d_ws;
        float* VSUM = P + P_elems;
        caps_pass<0, 0><<<grid, blk, 0, stream>>>(x, W, nullptr, P);
        reduce_squash<<<rgrid, blk, 0, stream>>>(P, N_IG, VSUM, out, 0);
        caps_pass<1, 0><<<grid, blk, 0, stream>>>(x, W, VSUM, P);
        reduce_squash<<<rgrid, blk, 0, stream>>>(P, N_IG, VSUM, out, 1);
        caps_pass<1, 0><<<grid, blk, 0, stream>>>(x, W, VSUM, P);
        reduce_squash<<<rgrid, blk, 0, stream>>>(P, N_IG, VSUM, out, 2);
    } else {
        // atomic fallback
        float* S    = (float*)d_ws;
        float* VSUM = S + (size_t)B_TOT * JD;
        const size_t sbytes = (size_t)B_TOT * JD * sizeof(float);
        hipMemsetAsync(S, 0, sbytes, stream);
        caps_pass<0, 1><<<grid, blk, 0, stream>>>(x, W, nullptr, S);
        reduce_squash<<<rgrid, blk, 0, stream>>>(S, 1, VSUM, out, 0);
        hipMemsetAsync(S, 0, sbytes, stream);
        caps_pass<1, 1><<<grid, blk, 0, stream>>>(x, W, VSUM, S);
        reduce_squash<<<rgrid, blk, 0, stream>>>(S, 1, VSUM, out, 1);
        hipMemsetAsync(S, 0, sbytes, stream);
        caps_pass<1, 1><<<grid, blk, 0, stream>>>(x, W, VSUM, S);
        reduce_squash<<<rgrid, blk, 0, stream>>>(S, 1, VSUM, out, 2);
    }
}